// Round 9
// baseline (89.661 us; speedup 1.0000x reference)
//
#include <hip/hip_runtime.h>
#include <hip/hip_bf16.h>

#define Bn 8
#define Sn 2048
#define Dn 512
#define Kn 64

typedef _Float16 half8 __attribute__((ext_vector_type(8)));
typedef _Float16 half4v __attribute__((ext_vector_type(4)));
typedef float f32x4 __attribute__((ext_vector_type(4)));

#define MFMA16(a,b,c) __builtin_amdgcn_mfma_f32_16x16x32_f16(a,b,c,0,0,0)
#define LOG2E 1.4426950408889634f

__device__ __forceinline__ void glds16(const void* g, void* l){
    __builtin_amdgcn_global_load_lds(
        (const __attribute__((address_space(1))) unsigned int*)g,
        (__attribute__((address_space(3))) unsigned int*)l, 16, 0, 0);
}

// LDS tiles [rows][64] f16 (128B rows), XOR-swizzled on 16B granules.
__device__ __forceinline__ half8 ldfrag(const _Float16* base, int row, int k8){
    const int scol = k8 ^ (row & 7);
    return *(const half8*)((const char*)base + row*128 + scol*16);
}

// Fragment layouts in global memory (16B granules, lane = l4*16+l15):
//  Qh2/Kh2: granule (t*2+ks)*64+lane = M[t*16+l15][ks*32+l4*8 .. +8]   (t = global 16-row tile)
//  Vt2:     granule (((b*32+sc)*2+ks)*32+dt)*64+lane = V[dt*16+l15][sc*64+(ks*4+l4)*8 .. +8]
// Q pre-scaled by log2(e). Stats: z[s] = sum_q 2^(l2-64); CS[s] = -(64+log2 z).
// attn: P[q,s] = 2^(l2[q,s] + CS[s]) via MFMA C-init.

// ---- Kernel 0: W transpose+cast ----
__global__ __launch_bounds__(256) void wtrans_kernel(
    const float* __restrict__ Wk, const float* __restrict__ Wq,
    _Float16* __restrict__ Wt16)
{
    const int n = blockIdx.x;
    const int t = threadIdx.x;
    const float* src = (n < 64) ? Wq : Wk;
    const int nn = n & 63;
    #pragma unroll
    for (int i = 0; i < 2; ++i){
        const int k = t + 256*i;
        Wt16[(size_t)n*Dn + k] = (_Float16)src[(size_t)k*Kn + nn];
    }
}

// ---- Kernel 1: fused Q/K projection + V transpose (32 rows per block) ----
__global__ __launch_bounds__(256, 2) void prep_kernel(
    const float* __restrict__ X, const _Float16* __restrict__ Wt16,
    const float* __restrict__ bk, const float* __restrict__ bq,
    _Float16* __restrict__ Qh2, _Float16* __restrict__ Kh2,
    _Float16* __restrict__ Vt2)
{
    __shared__ _Float16 Xt[2][32*64];
    const int bid = blockIdx.x;
    const int b = bid & 7, sb32 = bid >> 3;
    const int tid = threadIdx.x, lane = tid & 63, w = tid >> 6;
    const int l15 = lane & 15, l4 = lane >> 4;

    const int srow = tid >> 3, sg = tid & 7;
    const float* Xs = X + ((size_t)(b*Sn + sb32*32) + srow)*Dn + sg*8;
    const int sdst = srow*128 + (((sg ^ (srow & 7) ^ (srow >> 3)) & 7) * 16);

    const int n0 = w*32 + l15;
    const _Float16* Wp0 = Wt16 + (size_t)n0*Dn + l4*8;
    const _Float16* Wp1 = Wp0 + (size_t)16*Dn;

    f32x4 acc[2][2];
    #pragma unroll
    for (int i = 0; i < 2; ++i)
        #pragma unroll
        for (int j = 0; j < 2; ++j){ f32x4 z = {0.f,0.f,0.f,0.f}; acc[i][j] = z; }

    {
        const float4 v0 = *(const float4*)(Xs);
        const float4 v1 = *(const float4*)(Xs + 4);
        half8 h;
        h[0]=(_Float16)v0.x; h[1]=(_Float16)v0.y; h[2]=(_Float16)v0.z; h[3]=(_Float16)v0.w;
        h[4]=(_Float16)v1.x; h[5]=(_Float16)v1.y; h[6]=(_Float16)v1.z; h[7]=(_Float16)v1.w;
        *(half8*)((char*)Xt[0] + sdst) = h;
    }
    __syncthreads();

    const int dcol = w*16 + l15;
    #pragma unroll
    for (int kc = 0; kc < 8; ++kc){
        const _Float16* XtC = Xt[kc & 1];
        float4 nv0, nv1;
        if (kc < 7){
            nv0 = *(const float4*)(Xs + (kc+1)*64);
            nv1 = *(const float4*)(Xs + (kc+1)*64 + 4);
        }
        const half8 wf00 = *(const half8*)(Wp0 + kc*64);
        const half8 wf01 = *(const half8*)(Wp0 + kc*64 + 32);
        const half8 wf10 = *(const half8*)(Wp1 + kc*64);
        const half8 wf11 = *(const half8*)(Wp1 + kc*64 + 32);
        #pragma unroll
        for (int ks = 0; ks < 2; ++ks){
            #pragma unroll
            for (int qt = 0; qt < 2; ++qt){
                const int rw = qt*16 + l15;
                const int g = ((ks*4 + l4) ^ (rw & 7) ^ (rw >> 3)) & 7;
                const half8 a = *(const half8*)((const char*)XtC + rw*128 + g*16);
                acc[qt][0] = MFMA16(a, ks ? wf01 : wf00, acc[qt][0]);
                acc[qt][1] = MFMA16(a, ks ? wf11 : wf10, acc[qt][1]);
            }
        }
        {
            half8 hv;
            #pragma unroll
            for (int e = 0; e < 8; ++e){
                const int rw = l4*8 + e;
                const int g = ((dcol >> 3) ^ e ^ l4) & 7;
                hv[e] = XtC[rw*64 + g*8 + (dcol & 7)];
            }
            const size_t G = (((size_t)(b*32 + (sb32 >> 1))*2 + (sb32 & 1))*32 + kc*4 + w)*64 + lane;
            *(half8*)(Vt2 + G*8) = hv;
        }
        if (kc < 7){
            half8 h;
            h[0]=(_Float16)nv0.x; h[1]=(_Float16)nv0.y; h[2]=(_Float16)nv0.z; h[3]=(_Float16)nv0.w;
            h[4]=(_Float16)nv1.x; h[5]=(_Float16)nv1.y; h[6]=(_Float16)nv1.z; h[7]=(_Float16)nv1.w;
            *(half8*)((char*)Xt[(kc+1) & 1] + sdst) = h;
        }
        __syncthreads();
    }

    _Float16* tile16 = &Xt[0][0];
    #pragma unroll
    for (int qt = 0; qt < 2; ++qt){
        const int ql = qt*16 + l4*4;
        #pragma unroll
        for (int nt = 0; nt < 2; ++nt){
            const int n = w*32 + nt*16 + l15;
            const bool isQ = (n < 64);
            const float bias = isQ ? bq[n] : bk[n - 64];
            const float scale = isQ ? LOG2E : 1.0f;
            #pragma unroll
            for (int r = 0; r < 4; ++r)
                tile16[(ql + r)*128 + n] = (_Float16)((acc[qt][nt][r] + bias) * scale);
        }
    }
    __syncthreads();
    #pragma unroll
    for (int i = 0; i < 2; ++i){
        const int g = tid + 256*i;
        const int isK = g >> 8, qtl = (g >> 7) & 1, ks = (g >> 6) & 1, ln = g & 63;
        const int l4g = ln >> 4, l15g = ln & 15;
        const half8 h = *(const half8*)&tile16[(qtl*16 + l15g)*128 + isK*64 + ks*32 + l4g*8];
        const size_t tg = (size_t)b*128 + sb32*2 + qtl;
        _Float16* dst = (isK ? Kh2 : Qh2) + ((tg*2 + ks)*64 + ln)*8;
        *(half8*)dst = h;
    }
}

// ---- Kernel 2: per-(b,s) column denominators (base-2, fixed M0=64) ----
#define SBODY(QC0,QC1,QC2,QC3, QN0,QN1,QN2,QN3) do { \
    QN0 = *(const half8*)(Qp); \
    QN1 = *(const half8*)(Qp + 1024); \
    QN2 = *(const half8*)(Qp + 2048); \
    QN3 = *(const half8*)(Qp + 3072); \
    Qp += 8192; \
    f32x4 c0 = cinit, c1 = cinit; \
    c0 = MFMA16(ka0, QC0, c0); c0 = MFMA16(ka1, QC1, c0); \
    c1 = MFMA16(ka0, QC2, c1); c1 = MFMA16(ka1, QC3, c1); \
    _Pragma("unroll") \
    for (int r = 0; r < 4; ++r) \
        z[r] += exp2f(c0[r]) + exp2f(c1[r]); \
} while(0)

__global__ __launch_bounds__(512, 2) void stats_kernel(
    const _Float16* __restrict__ Qh2, const _Float16* __restrict__ Kh2,
    float* __restrict__ CS)
{
    __shared__ float zred[2][64];
    const int bid = blockIdx.x;
    const int b = bid & 7, stb = bid >> 3;
    const int tid = threadIdx.x, lane = tid & 63, w = tid >> 6;
    const int l15 = lane & 15, l4 = lane >> 4;
    const int sw = w & 3, qh = w >> 2, qh2 = qh*2;

    const half8 ka0 = *(const half8*)(Kh2 + ((size_t)((b*128 + stb*4 + sw)*2 + 0)*64 + lane)*8);
    const half8 ka1 = *(const half8*)(Kh2 + ((size_t)((b*128 + stb*4 + sw)*2 + 1)*64 + lane)*8);

    const char* Qp = (const char*)Qh2 + (size_t)(b*128 + qh2)*2048 + lane*16;

    const f32x4 cinit = {-64.f, -64.f, -64.f, -64.f};
    float z[4] = {0.f, 0.f, 0.f, 0.f};

    half8 qbA0, qbA1, qbA2, qbA3, qbB0, qbB1, qbB2, qbB3;
    qbA0 = *(const half8*)(Qp);
    qbA1 = *(const half8*)(Qp + 1024);
    qbA2 = *(const half8*)(Qp + 2048);
    qbA3 = *(const half8*)(Qp + 3072);
    Qp += 8192;

    for (int qc = 0; qc < 32; qc += 2){
        SBODY(qbA0,qbA1,qbA2,qbA3, qbB0,qbB1,qbB2,qbB3);
        SBODY(qbB0,qbB1,qbB2,qbB3, qbA0,qbA1,qbA2,qbA3);
    }
    #pragma unroll
    for (int d = 1; d < 16; d <<= 1)
        #pragma unroll
        for (int r = 0; r < 4; ++r)
            z[r] += __shfl_xor(z[r], d);
    if (l15 == 0){
        const int sl = sw*16 + l4*4;
        #pragma unroll
        for (int r = 0; r < 4; ++r) zred[qh][sl+r] = z[r];
    }
    __syncthreads();
    if (tid < 64)
        CS[b*Sn + stb*64 + tid] = -(64.0f + __log2f(zred[0][tid] + zred[1][tid]));
}

// ---- Kernel 4: attn, 128q x 256d block, 8 waves, LDS-V + counted vmcnt ----
#define WRP(CUR, QT, C) do { \
    half4v p; \
    p[0] = (_Float16)exp2f(C[0]); \
    p[1] = (_Float16)exp2f(C[1]); \
    p[2] = (_Float16)exp2f(C[2]); \
    p[3] = (_Float16)exp2f(C[3]); \
    *(half4v*)((char*)Pt[CUR] + pwo[QT]) = p; \
} while(0)

#define ABODY(CUR, KA, KAN, CSA, CSN, SCV) do { \
    { const size_t sb_ = Vbase + (size_t)((SCV)+1)*65536; \
      _Pragma("unroll") \
      for (int j = 0; j < 4; ++j) \
        glds16(Vt2c + sb_ + soff[j], (char*)VL[(CUR)^1] + (w*4+j)*1024); } \
    f32x4 c0 = {CSA.x, CSA.y, CSA.z, CSA.w}; \
    f32x4 c1 = c0, c2 = c0, c3 = c0; \
    c0 = MFMA16(KA[0], qb[0][0], c0); c0 = MFMA16(KA[1], qb[0][1], c0); \
    c1 = MFMA16(KA[0], qb[1][0], c1); c1 = MFMA16(KA[1], qb[1][1], c1); \
    c2 = MFMA16(KA[0], qb[2][0], c2); c2 = MFMA16(KA[1], qb[2][1], c2); \
    c3 = MFMA16(KA[0], qb[3][0], c3); c3 = MFMA16(KA[1], qb[3][1], c3); \
    KAN[0] = *(const half8*)(Kp); \
    KAN[1] = *(const half8*)(Kp + 1024); \
    Kp += 8192; \
    CSN = *(const float4*)Cp; Cp += 64; \
    WRP(CUR, 0, c0); WRP(CUR, 1, c1); WRP(CUR, 2, c2); WRP(CUR, 3, c3); \
    asm volatile("s_waitcnt lgkmcnt(0) vmcnt(4)\n\ts_barrier" ::: "memory"); \
    { const char* PB = (const char*)Pt[CUR]; \
      const char* VB_ = (const char*)VL[CUR]; \
      _Pragma("unroll") \
      for (int ks = 0; ks < 2; ++ks){ \
        const half8 pa0 = *(const half8*)(PB + pao[0][ks]); \
        const half8 pa1 = *(const half8*)(PB + pao[1][ks]); \
        const half8 pa2 = *(const half8*)(PB + pao[2][ks]); \
        const half8 pa3 = *(const half8*)(PB + pao[3][ks]); \
        _Pragma("unroll") \
        for (int dt = 0; dt < 4; ++dt){ \
            const half8 vb = *(const half8*)(VB_ + vbo[ks][dt]); \
            acc[0][dt] = MFMA16(pa0, vb, acc[0][dt]); \
            acc[1][dt] = MFMA16(pa1, vb, acc[1][dt]); \
            acc[2][dt] = MFMA16(pa2, vb, acc[2][dt]); \
            acc[3][dt] = MFMA16(pa3, vb, acc[3][dt]); \
        } \
      } } \
    asm volatile("s_barrier" ::: "memory"); \
} while(0)

__global__ __launch_bounds__(512, 2) void attn_kernel(
    const _Float16* __restrict__ Qh2, const _Float16* __restrict__ Kh2,
    const _Float16* __restrict__ Vt2, const float* __restrict__ CS,
    float* __restrict__ out)
{
    __shared__ _Float16 Pt[2][128*64];   // 32 KB
    __shared__ _Float16 VL[2][32*512];   // 64 KB (32 granule-groups x 1024B)
    const int bid = blockIdx.x;
    const int b  = bid & 7;              // b-major -> one batch per XCD
    const int qi = (bid >> 3) & 15;
    const int dh = bid >> 7;             // 0..1 d-half (256 each)
    const int q0 = qi * 128;
    const int tid = threadIdx.x, lane = tid & 63, w = tid >> 6;  // w 0..7
    const int l15 = lane & 15, l4 = lane >> 4;
    const int st = w & 3, qh = w >> 2, dw = w & 3;

    // Q fragments: wave's 64q-half (4 qt x 2 ks)
    const size_t qgb = (size_t)b*128 + qi*8 + qh*4;
    half8 qb[4][2];
    #pragma unroll
    for (int qt = 0; qt < 4; ++qt)
        #pragma unroll
        for (int ks = 0; ks < 2; ++ks)
            qb[qt][ks] = *(const half8*)(Qh2 + (((qgb + qt)*2 + ks)*64 + lane)*8);

    // precomputed LDS offsets
    int pwo[4], pao[4][2], vbo[2][4];
    {
        const int sb2 = (st*16 + l4*4) * 2;
        #pragma unroll
        for (int qt = 0; qt < 4; ++qt){
            const int q_ = qh*64 + qt*16 + l15;
            pwo[qt] = q_*128 + (sb2 ^ ((q_ & 7) << 4));
            #pragma unroll
            for (int ks = 0; ks < 2; ++ks)
                pao[qt][ks] = q_*128 + (((ks*4 + l4) ^ (q_ & 7)) * 16);
        }
        #pragma unroll
        for (int ks = 0; ks < 2; ++ks)
            #pragma unroll
            for (int dt = 0; dt < 4; ++dt)
                vbo[ks][dt] = (ks*16 + dw*4 + dt)*1024 + lane*16;
    }
    // stage source offsets (wave stages granule-groups w*4..w*4+3)
    const char* Vt2c = (const char*)Vt2;
    const size_t Vbase = (size_t)b * (32*65536);
    size_t soff[4];
    #pragma unroll
    for (int j = 0; j < 4; ++j){
        const int gi = w*4 + j;
        soff[j] = (size_t)(((gi >> 4)*32) + dh*16 + (gi & 15))*1024 + lane*16;
    }

    // streams
    const char* Kp = (const char*)Kh2 + (size_t)(b*128 + st)*2048 + lane*16;
    const float* Cp = CS + b*Sn + st*16 + l4*4;

    // prologue: K(0), CS(0), stage V(0) into VL[0]
    half8 kaA[2], kaB[2];
    float4 csA, csB;
    kaA[0] = *(const half8*)(Kp);
    kaA[1] = *(const half8*)(Kp + 1024);
    Kp += 8192;
    csA = *(const float4*)Cp; Cp += 64;
    #pragma unroll
    for (int j = 0; j < 4; ++j)
        glds16(Vt2c + Vbase + soff[j], (char*)VL[0] + (w*4+j)*1024);

    f32x4 acc[4][4];
    #pragma unroll
    for (int i = 0; i < 4; ++i)
        #pragma unroll
        for (int j = 0; j < 4; ++j){ f32x4 zz4 = {0.f,0.f,0.f,0.f}; acc[i][j] = zz4; }

    for (int sc = 0; sc < 32; sc += 2){
        ABODY(0, kaA, kaB, csA, csB, sc);
        ABODY(1, kaB, kaA, csB, csA, sc+1);
    }

    float* ob = out + (size_t)(b*Sn + q0 + qh*64)*Dn + dh*256 + dw*64;
    #pragma unroll
    for (int qt = 0; qt < 4; ++qt){
        const int q = qt*16 + l4*4;
        #pragma unroll
        for (int dt = 0; dt < 4; ++dt){
            #pragma unroll
            for (int r = 0; r < 4; ++r)
                ob[(size_t)(q + r)*Dn + dt*16 + l15] = acc[qt][dt][r];
        }
    }
}

extern "C" void kernel_launch(void* const* d_in, const int* in_sizes, int n_in,
                              void* d_out, int out_size, void* d_ws, size_t ws_size,
                              hipStream_t stream)
{
    const float* X  = (const float*)d_in[0];
    const float* Wk = (const float*)d_in[1];
    const float* bk = (const float*)d_in[2];
    const float* Wq = (const float*)d_in[3];
    const float* bq = (const float*)d_in[4];
    float* out = (float*)d_out;

    char* ws = (char*)d_ws;
    _Float16* Qh2  = (_Float16*)ws;                                  // 2 MB
    _Float16* Kh2  = (_Float16*)(ws + ((size_t)2 << 20));            // 2 MB
    _Float16* Vt2  = (_Float16*)(ws + ((size_t)4 << 20));            // 16 MB
    float*    CS   = (float*)(ws + ((size_t)20 << 20));              // 64 KB (+guard)
    _Float16* Wt16 = (_Float16*)(ws + ((size_t)20 << 20) + (2 << 16)); // 128 KB

    wtrans_kernel<<<dim3(128), dim3(256), 0, stream>>>(Wk, Wq, Wt16);
    prep_kernel<<<dim3(Bn*(Sn/32)), dim3(256), 0, stream>>>(X, Wt16, bk, bq, Qh2, Kh2, Vt2);
    stats_kernel<<<dim3(Bn*(Sn/64)), dim3(512), 0, stream>>>(Qh2, Kh2, CS);
    attn_kernel<<<dim3(Bn*(Sn/128)*2), dim3(512), 0, stream>>>(Qh2, Kh2, Vt2, CS, out);
}